// Round 1
// baseline (1243.494 us; speedup 1.0000x reference)
//
#include <hip/hip_runtime.h>
#include <hip/hip_bf16.h>
#include <math.h>

#define N_NODES 100000
#define F_IN 512
#define HEADS 8
#define CH 8
#define HC 64           // HEADS*CH
#define NOUT 16
#define NE 3200000
#define E_TOT (NE + N_NODES)   // 3,300,000 (edges + self loops)
#define LEAKY 0.2f

// ---------------------------------------------------------------------------
// K1: h1[N,64] = x[N,512] @ W1[512,64]   (fp32, tiled, BM=64 BN=64 BK=64)
// ---------------------------------------------------------------------------
__global__ __launch_bounds__(256) void gemm1_kernel(
    const float* __restrict__ x, const float* __restrict__ W,
    float* __restrict__ h1) {
  __shared__ __align__(16) float xs[64][68];   // +4 pad: breaks row-stride bank conflicts
  __shared__ __align__(16) float ws[64][64];
  const int t  = threadIdx.x;
  const int bm = blockIdx.x * 64;
  const int ty = t >> 4, tx = t & 15;
  const int lr = t >> 4;      // 0..15
  const int lc = t & 15;      // 0..15 (float4 column)
  float acc[4][4] = {{0.f,0.f,0.f,0.f},{0.f,0.f,0.f,0.f},
                     {0.f,0.f,0.f,0.f},{0.f,0.f,0.f,0.f}};

  for (int k0 = 0; k0 < F_IN; k0 += 64) {
    #pragma unroll
    for (int i = 0; i < 4; i++) {              // x tile: 64 rows x 64 k
      int row = lr + i * 16;
      int gr  = bm + row;
      float4 v = make_float4(0.f, 0.f, 0.f, 0.f);
      if (gr < N_NODES)
        v = *(const float4*)(x + (size_t)gr * F_IN + k0 + lc * 4);
      *(float4*)&xs[row][lc * 4] = v;
    }
    #pragma unroll
    for (int i = 0; i < 4; i++) {              // W tile: 64 k x 64 cols
      int kr = lr + i * 16;
      float4 v = *(const float4*)(W + (size_t)(k0 + kr) * HC + lc * 4);
      *(float4*)&ws[kr][lc * 4] = v;
    }
    __syncthreads();
    #pragma unroll 16
    for (int k = 0; k < 64; k++) {
      float a0 = xs[ty * 4 + 0][k], a1 = xs[ty * 4 + 1][k];
      float a2 = xs[ty * 4 + 2][k], a3 = xs[ty * 4 + 3][k];
      float4 b = *(const float4*)&ws[k][tx * 4];
      acc[0][0] += a0 * b.x; acc[0][1] += a0 * b.y; acc[0][2] += a0 * b.z; acc[0][3] += a0 * b.w;
      acc[1][0] += a1 * b.x; acc[1][1] += a1 * b.y; acc[1][2] += a1 * b.z; acc[1][3] += a1 * b.w;
      acc[2][0] += a2 * b.x; acc[2][1] += a2 * b.y; acc[2][2] += a2 * b.z; acc[2][3] += a2 * b.w;
      acc[3][0] += a3 * b.x; acc[3][1] += a3 * b.y; acc[3][2] += a3 * b.z; acc[3][3] += a3 * b.w;
    }
    __syncthreads();
  }
  #pragma unroll
  for (int i = 0; i < 4; i++) {
    int gr = bm + ty * 4 + i;
    if (gr < N_NODES)
      *(float4*)(h1 + (size_t)gr * HC + tx * 4) =
          make_float4(acc[i][0], acc[i][1], acc[i][2], acc[i][3]);
  }
}

// ---------------------------------------------------------------------------
// K1b: f_self1/f_neigh1[N,8] = per-head dot(h1[n,h,:], a_*[h,:])
// grid = N*HEADS threads exactly (800000 = 3125*256)
// ---------------------------------------------------------------------------
__global__ __launch_bounds__(256) void f1_kernel(
    const float* __restrict__ h1, const float* __restrict__ a_self,
    const float* __restrict__ a_neigh, float* __restrict__ fs,
    float* __restrict__ fn) {
  int tid = blockIdx.x * 256 + threadIdx.x;   // n*8 + h
  int h = tid & 7;
  const float4* hp = (const float4*)(h1 + (size_t)tid * 8);
  float4 v0 = hp[0], v1 = hp[1];
  const float4* as = (const float4*)(a_self + h * 8);
  const float4* an = (const float4*)(a_neigh + h * 8);
  float4 s0 = as[0], s1 = as[1];
  float4 n0 = an[0], n1 = an[1];
  fs[tid] = v0.x*s0.x + v0.y*s0.y + v0.z*s0.z + v0.w*s0.w
          + v1.x*s1.x + v1.y*s1.y + v1.z*s1.z + v1.w*s1.w;
  fn[tid] = v0.x*n0.x + v0.y*n0.y + v0.z*n0.z + v0.w*n0.w
          + v1.x*n1.x + v1.y*n1.y + v1.z*n1.z + v1.w*n1.w;
}

// ---------------------------------------------------------------------------
// K2a: degree histogram over dst (self-loops implicit for e >= NE)
// ---------------------------------------------------------------------------
__global__ __launch_bounds__(256) void hist_kernel(
    const int* __restrict__ edge_dst, int* __restrict__ deg) {
  int e = blockIdx.x * 256 + threadIdx.x;
  if (e >= E_TOT) return;
  int d = (e < NE) ? edge_dst[e] : (e - NE);
  atomicAdd(&deg[d], 1);
}

// ---------------------------------------------------------------------------
// K2b: exclusive scan of deg -> row_start[N+1], cursor[N]  (single block)
// ---------------------------------------------------------------------------
__global__ __launch_bounds__(1024) void scan_kernel(
    const int* __restrict__ deg, int* __restrict__ row_start,
    int* __restrict__ cursor) {
  __shared__ int sdata[1024];
  __shared__ int sbase;
  int t = threadIdx.x;
  if (t == 0) sbase = 0;
  __syncthreads();
  for (int chunk = 0; chunk < N_NODES; chunk += 1024) {
    int i = chunk + t;
    int v = (i < N_NODES) ? deg[i] : 0;
    sdata[t] = v;
    __syncthreads();
    for (int off = 1; off < 1024; off <<= 1) {
      int y = (t >= off) ? sdata[t - off] : 0;
      __syncthreads();
      sdata[t] += y;
      __syncthreads();
    }
    int incl = sdata[t];
    int base = sbase;
    if (i < N_NODES) {
      int excl = base + incl - v;
      row_start[i] = excl;
      cursor[i]    = excl;
    }
    __syncthreads();
    if (t == 1023) sbase = base + sdata[1023];
    __syncthreads();
  }
  if (t == 0) row_start[N_NODES] = sbase;
}

// ---------------------------------------------------------------------------
// K2c: scatter edges into CSR-by-dst (store src only; logits recomputed)
// ---------------------------------------------------------------------------
__global__ __launch_bounds__(256) void scatter_kernel(
    const int* __restrict__ edge_src, const int* __restrict__ edge_dst,
    int* __restrict__ cursor, int* __restrict__ csr_src) {
  int e = blockIdx.x * 256 + threadIdx.x;
  if (e >= E_TOT) return;
  int s, d;
  if (e < NE) { s = edge_src[e]; d = edge_dst[e]; }
  else        { s = e - NE;      d = e - NE; }
  int p = atomicAdd(&cursor[d], 1);
  csr_src[p] = s;
}

// ---------------------------------------------------------------------------
// K3: layer-1 aggregation. 8 lanes per node (one per head).
//     Per node: 2 edge passes (max; exp+weighted sum), then fused
//     bias+ELU -> h2 = out1 @ W2 -> f_self2/f_neigh2.
// grid = N*HEADS = 800000 threads exactly (3125*256)
// ---------------------------------------------------------------------------
__global__ __launch_bounds__(256) void layer1_kernel(
    const int* __restrict__ row_start, const int* __restrict__ csr_src,
    const float* __restrict__ fs1, const float* __restrict__ fn1,
    const float* __restrict__ h1, const float* __restrict__ b1,
    const float* __restrict__ W2, const float* __restrict__ a_self2,
    const float* __restrict__ a_neigh2, float* __restrict__ h2,
    float* __restrict__ fs2, float* __restrict__ fn2) {
  __shared__ float w2s[HC][NOUT];
  for (int i = threadIdx.x; i < HC * NOUT; i += 256)
    w2s[i / NOUT][i % NOUT] = W2[i];
  __syncthreads();

  int tid = blockIdx.x * 256 + threadIdx.x;   // n*8 + h
  int n = tid >> 3, h = tid & 7;
  float fs = fs1[tid];
  int jb = row_start[n], je = row_start[n + 1];

  // pass 1: per-head max logit over incoming edges
  float mx = -1e30f;
  for (int j = jb; j < je; j++) {
    int src = csr_src[j];
    float l = fs + fn1[src * HEADS + h];
    l = (l > 0.f) ? l : LEAKY * l;
    mx = fmaxf(mx, l);
  }
  // pass 2: exp-weights + weighted feature sum
  float acc[CH] = {0.f,0.f,0.f,0.f,0.f,0.f,0.f,0.f};
  float den = 0.f;
  for (int j = jb; j < je; j++) {
    int src = csr_src[j];
    float l = fs + fn1[src * HEADS + h];
    l = (l > 0.f) ? l : LEAKY * l;
    float w = expf(l - mx);
    den += w;
    const float4* hp = (const float4*)(h1 + (size_t)src * HC + h * CH);
    float4 v0 = hp[0], v1 = hp[1];
    acc[0] += w * v0.x; acc[1] += w * v0.y; acc[2] += w * v0.z; acc[3] += w * v0.w;
    acc[4] += w * v1.x; acc[5] += w * v1.y; acc[6] += w * v1.z; acc[7] += w * v1.w;
  }
  float inv = 1.f / (den + 1e-9f);

  // bias + ELU (this lane's 8 channels of the 64-wide concat output)
  const float4* bp = (const float4*)(b1 + h * 8);
  float4 b0 = bp[0], b1v = bp[1];
  float o[CH];
  o[0] = acc[0]*inv + b0.x; o[1] = acc[1]*inv + b0.y;
  o[2] = acc[2]*inv + b0.z; o[3] = acc[3]*inv + b0.w;
  o[4] = acc[4]*inv + b1v.x; o[5] = acc[5]*inv + b1v.y;
  o[6] = acc[6]*inv + b1v.z; o[7] = acc[7]*inv + b1v.w;
  #pragma unroll
  for (int c = 0; c < CH; c++) o[c] = (o[c] > 0.f) ? o[c] : expm1f(o[c]);

  // fused layer-2 projection: h2[n, :] = out1[n, :] @ W2[64,16]
  float pj[NOUT];
  #pragma unroll
  for (int c2 = 0; c2 < NOUT; c2++) {
    float s = 0.f;
    #pragma unroll
    for (int c = 0; c < CH; c++) s += o[c] * w2s[h * CH + c][c2];
    pj[c2] = s;
  }
  // butterfly-sum over the 8 head-lanes of this node
  #pragma unroll
  for (int m = 1; m < 8; m <<= 1) {
    #pragma unroll
    for (int c2 = 0; c2 < NOUT; c2++)
      pj[c2] += __shfl_xor(pj[c2], m, 64);
  }
  // coalesced h2 write: lane h writes elements [h*2, h*2+1]
  *(float2*)(h2 + (size_t)n * NOUT + h * 2) = make_float2(pj[h * 2], pj[h * 2 + 1]);
  if (h == 0) {
    float s1 = 0.f, s2 = 0.f;
    #pragma unroll
    for (int c2 = 0; c2 < NOUT; c2++) {
      s1 += pj[c2] * a_self2[c2];
      s2 += pj[c2] * a_neigh2[c2];
    }
    fs2[n] = s1;
    fn2[n] = s2;
  }
}

// ---------------------------------------------------------------------------
// K4: layer-2 aggregation (1 head, 16 ch). 4 lanes per node, 4 ch each.
//     Fused: bias + row-softmax -> final output.
// ---------------------------------------------------------------------------
__global__ __launch_bounds__(256) void layer2_kernel(
    const int* __restrict__ row_start, const int* __restrict__ csr_src,
    const float* __restrict__ fs2, const float* __restrict__ fn2,
    const float* __restrict__ h2, const float* __restrict__ b2,
    float* __restrict__ out) {
  int tid = blockIdx.x * 256 + threadIdx.x;   // n*4 + q
  if (tid >= N_NODES * 4) return;             // whole-wave exit (400000 % 64 == 0)
  int n = tid >> 2, q = tid & 3;
  float fs = fs2[n];
  int jb = row_start[n], je = row_start[n + 1];

  float mx = -1e30f;
  for (int j = jb; j < je; j++) {
    float l = fs + fn2[csr_src[j]];
    l = (l > 0.f) ? l : LEAKY * l;
    mx = fmaxf(mx, l);
  }
  float4 acc = make_float4(0.f, 0.f, 0.f, 0.f);
  float den = 0.f;
  for (int j = jb; j < je; j++) {
    int src = csr_src[j];
    float l = fs + fn2[src];
    l = (l > 0.f) ? l : LEAKY * l;
    float w = expf(l - mx);
    den += w;
    float4 v = *(const float4*)(h2 + (size_t)src * NOUT + q * 4);
    acc.x += w * v.x; acc.y += w * v.y; acc.z += w * v.z; acc.w += w * v.w;
  }
  float inv = 1.f / (den + 1e-9f);
  const float4* bp = (const float4*)(b2 + q * 4);
  float4 bv = bp[0];
  float o0 = acc.x * inv + bv.x, o1 = acc.y * inv + bv.y;
  float o2 = acc.z * inv + bv.z, o3 = acc.w * inv + bv.w;

  // softmax over 16 channels across the 4-lane group
  float m = fmaxf(fmaxf(o0, o1), fmaxf(o2, o3));
  m = fmaxf(m, __shfl_xor(m, 1, 64));
  m = fmaxf(m, __shfl_xor(m, 2, 64));
  float e0 = expf(o0 - m), e1 = expf(o1 - m), e2 = expf(o2 - m), e3 = expf(o3 - m);
  float s = e0 + e1 + e2 + e3;
  s += __shfl_xor(s, 1, 64);
  s += __shfl_xor(s, 2, 64);
  float invs = 1.f / s;
  *(float4*)(out + (size_t)n * NOUT + q * 4) =
      make_float4(e0 * invs, e1 * invs, e2 * invs, e3 * invs);
}

// ---------------------------------------------------------------------------
extern "C" void kernel_launch(void* const* d_in, const int* in_sizes, int n_in,
                              void* d_out, int out_size, void* d_ws, size_t ws_size,
                              hipStream_t stream) {
  const float* x        = (const float*)d_in[0];
  const float* W1       = (const float*)d_in[1];
  const float* a_self1  = (const float*)d_in[2];
  const float* a_neigh1 = (const float*)d_in[3];
  const float* b1       = (const float*)d_in[4];
  const float* W2       = (const float*)d_in[5];
  const float* a_self2  = (const float*)d_in[6];
  const float* a_neigh2 = (const float*)d_in[7];
  const float* b2       = (const float*)d_in[8];
  const int* edge_src   = (const int*)d_in[9];
  const int* edge_dst   = (const int*)d_in[10];
  float* out = (float*)d_out;

  // workspace carve-out (all offsets 256B-aligned), total ~53.5 MB
  char* p = (char*)d_ws;
  auto alloc = [&](size_t bytes) -> void* {
    void* r = (void*)p;
    p += (bytes + 255) & ~(size_t)255;
    return r;
  };
  float* h1   = (float*)alloc((size_t)N_NODES * HC * 4);
  float* fs1  = (float*)alloc((size_t)N_NODES * HEADS * 4);
  float* fn1  = (float*)alloc((size_t)N_NODES * HEADS * 4);
  float* h2   = (float*)alloc((size_t)N_NODES * NOUT * 4);
  float* fs2  = (float*)alloc((size_t)N_NODES * 4);
  float* fn2  = (float*)alloc((size_t)N_NODES * 4);
  int* deg       = (int*)alloc((size_t)N_NODES * 4);
  int* row_start = (int*)alloc((size_t)(N_NODES + 1) * 4);
  int* cursor    = (int*)alloc((size_t)N_NODES * 4);
  int* csr_src   = (int*)alloc((size_t)E_TOT * 4);

  hipMemsetAsync(deg, 0, (size_t)N_NODES * 4, stream);

  gemm1_kernel<<<(N_NODES + 63) / 64, 256, 0, stream>>>(x, W1, h1);
  f1_kernel<<<(N_NODES * HEADS) / 256, 256, 0, stream>>>(h1, a_self1, a_neigh1, fs1, fn1);
  hist_kernel<<<(E_TOT + 255) / 256, 256, 0, stream>>>(edge_dst, deg);
  scan_kernel<<<1, 1024, 0, stream>>>(deg, row_start, cursor);
  scatter_kernel<<<(E_TOT + 255) / 256, 256, 0, stream>>>(edge_src, edge_dst, cursor, csr_src);
  layer1_kernel<<<(N_NODES * HEADS) / 256, 256, 0, stream>>>(
      row_start, csr_src, fs1, fn1, h1, b1, W2, a_self2, a_neigh2, h2, fs2, fn2);
  layer2_kernel<<<(N_NODES * 4 + 255) / 256, 256, 0, stream>>>(
      row_start, csr_src, fs2, fn2, h2, b2, out);
}

// Round 2
// 891.398 us; speedup vs baseline: 1.3950x; 1.3950x over previous
//
#include <hip/hip_runtime.h>
#include <hip/hip_bf16.h>
#include <math.h>

#define N_NODES 100000
#define F_IN 512
#define HEADS 8
#define CH 8
#define HC 64           // HEADS*CH
#define NOUT 16
#define NE 3200000
#define E_TOT (NE + N_NODES)   // 3,300,000 (edges + self loops)
#define LEAKY 0.2f

// ---------------------------------------------------------------------------
// K1: h1[N,64] = x[N,512] @ W1[512,64]   (fp32, tiled, BM=64 BN=64 BK=64)
//     Fused epilogue: fs1/fn1[N,8] = per-head dot(h1[n,h,:], a_*[h,:])
// ---------------------------------------------------------------------------
__global__ __launch_bounds__(256) void gemm1_f1_kernel(
    const float* __restrict__ x, const float* __restrict__ W,
    const float* __restrict__ a_self, const float* __restrict__ a_neigh,
    float* __restrict__ h1, float* __restrict__ fs1, float* __restrict__ fn1) {
  __shared__ __align__(16) float xs[64][68];   // +4 pad: breaks row-stride bank conflicts
  __shared__ __align__(16) float ws[64][64];
  const int t  = threadIdx.x;
  const int bm = blockIdx.x * 64;
  const int ty = t >> 4, tx = t & 15;
  const int lr = t >> 4;      // 0..15
  const int lc = t & 15;      // 0..15 (float4 column)
  float acc[4][4] = {{0.f,0.f,0.f,0.f},{0.f,0.f,0.f,0.f},
                     {0.f,0.f,0.f,0.f},{0.f,0.f,0.f,0.f}};

  for (int k0 = 0; k0 < F_IN; k0 += 64) {
    #pragma unroll
    for (int i = 0; i < 4; i++) {              // x tile: 64 rows x 64 k
      int row = lr + i * 16;
      int gr  = bm + row;
      float4 v = make_float4(0.f, 0.f, 0.f, 0.f);
      if (gr < N_NODES)
        v = *(const float4*)(x + (size_t)gr * F_IN + k0 + lc * 4);
      *(float4*)&xs[row][lc * 4] = v;
    }
    #pragma unroll
    for (int i = 0; i < 4; i++) {              // W tile: 64 k x 64 cols
      int kr = lr + i * 16;
      float4 v = *(const float4*)(W + (size_t)(k0 + kr) * HC + lc * 4);
      *(float4*)&ws[kr][lc * 4] = v;
    }
    __syncthreads();
    #pragma unroll 16
    for (int k = 0; k < 64; k++) {
      float a0 = xs[ty * 4 + 0][k], a1 = xs[ty * 4 + 1][k];
      float a2 = xs[ty * 4 + 2][k], a3 = xs[ty * 4 + 3][k];
      float4 b = *(const float4*)&ws[k][tx * 4];
      acc[0][0] += a0 * b.x; acc[0][1] += a0 * b.y; acc[0][2] += a0 * b.z; acc[0][3] += a0 * b.w;
      acc[1][0] += a1 * b.x; acc[1][1] += a1 * b.y; acc[1][2] += a1 * b.z; acc[1][3] += a1 * b.w;
      acc[2][0] += a2 * b.x; acc[2][1] += a2 * b.y; acc[2][2] += a2 * b.z; acc[2][3] += a2 * b.w;
      acc[3][0] += a3 * b.x; acc[3][1] += a3 * b.y; acc[3][2] += a3 * b.z; acc[3][3] += a3 * b.w;
    }
    __syncthreads();
  }

  // write h1 tile
  #pragma unroll
  for (int i = 0; i < 4; i++) {
    int gr = bm + ty * 4 + i;
    if (gr < N_NODES)
      *(float4*)(h1 + (size_t)gr * HC + tx * 4) =
          make_float4(acc[i][0], acc[i][1], acc[i][2], acc[i][3]);
  }

  // fused f1: this thread's 4 cols are half of head h = tx>>1
  const int h    = tx >> 1;
  const int part = tx & 1;
  float4 asv = *(const float4*)(a_self  + h * 8 + part * 4);
  float4 anv = *(const float4*)(a_neigh + h * 8 + part * 4);
  #pragma unroll
  for (int i = 0; i < 4; i++) {
    float ps = acc[i][0]*asv.x + acc[i][1]*asv.y + acc[i][2]*asv.z + acc[i][3]*asv.w;
    float pn = acc[i][0]*anv.x + acc[i][1]*anv.y + acc[i][2]*anv.z + acc[i][3]*anv.w;
    ps += __shfl_xor(ps, 1, 64);
    pn += __shfl_xor(pn, 1, 64);
    int gr = bm + ty * 4 + i;
    if (part == 0 && gr < N_NODES) {
      fs1[gr * 8 + h] = ps;
      fn1[gr * 8 + h] = pn;
    }
  }
}

// ---------------------------------------------------------------------------
// K2: linked-list build — next[e] = atomicExch(&head[dst], e)
//     next[] write is coalesced by e; atomics hit a 400 KB head[] array.
//     (head pre-memset to -1 by kernel_launch)
// ---------------------------------------------------------------------------
__global__ __launch_bounds__(256) void ll_build_kernel(
    const int* __restrict__ edge_dst, int* __restrict__ head,
    int* __restrict__ next) {
  int e = blockIdx.x * 256 + threadIdx.x;
  if (e >= E_TOT) return;
  int d = (e < NE) ? edge_dst[e] : (e - NE);
  next[e] = atomicExch(&head[d], e);
}

// ---------------------------------------------------------------------------
// K3: layer-1 aggregation. 8 lanes per node (one per head).
//     Single online-softmax walk over the linked list, then fused
//     bias+ELU -> h2 = out1 @ W2 -> f_self2/f_neigh2.
// grid = N*HEADS = 800000 threads exactly (3125*256)
// ---------------------------------------------------------------------------
__global__ __launch_bounds__(256) void layer1_kernel(
    const int* __restrict__ head, const int* __restrict__ next,
    const int* __restrict__ edge_src,
    const float* __restrict__ fs1, const float* __restrict__ fn1,
    const float* __restrict__ h1, const float* __restrict__ b1,
    const float* __restrict__ W2, const float* __restrict__ a_self2,
    const float* __restrict__ a_neigh2, float* __restrict__ h2,
    float* __restrict__ fs2, float* __restrict__ fn2) {
  __shared__ float w2s[HC][NOUT];
  for (int i = threadIdx.x; i < HC * NOUT; i += 256)
    w2s[i / NOUT][i % NOUT] = W2[i];
  __syncthreads();

  int tid = blockIdx.x * 256 + threadIdx.x;   // n*8 + h
  int n = tid >> 3, h = tid & 7;
  float fs = fs1[tid];

  // online-softmax walk (branchless rescale; exact: final m == true max)
  float m = -1e30f, den = 0.f;
  float acc[CH] = {0.f,0.f,0.f,0.f,0.f,0.f,0.f,0.f};
  int e = head[n];
  while (e >= 0) {
    int src = (e < NE) ? edge_src[e] : (e - NE);
    float l = fs + fn1[src * HEADS + h];
    l = (l > 0.f) ? l : LEAKY * l;
    float mn = fmaxf(m, l);
    float r = __expf(m - mn);          // 1 when no new max; 0 on first edge
    float w = __expf(l - mn);
    m = mn;
    const float4* hp = (const float4*)(h1 + (size_t)src * HC + h * CH);
    float4 v0 = hp[0], v1 = hp[1];
    den = den * r + w;
    acc[0] = acc[0]*r + w*v0.x; acc[1] = acc[1]*r + w*v0.y;
    acc[2] = acc[2]*r + w*v0.z; acc[3] = acc[3]*r + w*v0.w;
    acc[4] = acc[4]*r + w*v1.x; acc[5] = acc[5]*r + w*v1.y;
    acc[6] = acc[6]*r + w*v1.z; acc[7] = acc[7]*r + w*v1.w;
    e = next[e];
  }
  float inv = 1.f / (den + 1e-9f);

  // bias + ELU (this lane's 8 channels of the 64-wide concat output)
  const float4* bp = (const float4*)(b1 + h * 8);
  float4 b0 = bp[0], b1v = bp[1];
  float o[CH];
  o[0] = acc[0]*inv + b0.x; o[1] = acc[1]*inv + b0.y;
  o[2] = acc[2]*inv + b0.z; o[3] = acc[3]*inv + b0.w;
  o[4] = acc[4]*inv + b1v.x; o[5] = acc[5]*inv + b1v.y;
  o[6] = acc[6]*inv + b1v.z; o[7] = acc[7]*inv + b1v.w;
  #pragma unroll
  for (int c = 0; c < CH; c++) o[c] = (o[c] > 0.f) ? o[c] : expm1f(o[c]);

  // fused layer-2 projection: h2[n, :] = out1[n, :] @ W2[64,16]
  float pj[NOUT];
  #pragma unroll
  for (int c2 = 0; c2 < NOUT; c2++) {
    float s = 0.f;
    #pragma unroll
    for (int c = 0; c < CH; c++) s += o[c] * w2s[h * CH + c][c2];
    pj[c2] = s;
  }
  // butterfly-sum over the 8 head-lanes of this node
  #pragma unroll
  for (int mm = 1; mm < 8; mm <<= 1) {
    #pragma unroll
    for (int c2 = 0; c2 < NOUT; c2++)
      pj[c2] += __shfl_xor(pj[c2], mm, 64);
  }
  // coalesced h2 write: lane h writes elements [h*2, h*2+1]
  *(float2*)(h2 + (size_t)n * NOUT + h * 2) = make_float2(pj[h * 2], pj[h * 2 + 1]);
  if (h == 0) {
    float s1 = 0.f, s2 = 0.f;
    #pragma unroll
    for (int c2 = 0; c2 < NOUT; c2++) {
      s1 += pj[c2] * a_self2[c2];
      s2 += pj[c2] * a_neigh2[c2];
    }
    fs2[n] = s1;
    fn2[n] = s2;
  }
}

// ---------------------------------------------------------------------------
// K4: layer-2 aggregation (1 head, 16 ch). 4 lanes per node, 4 ch each.
//     Single online-softmax walk. Fused: bias + row-softmax -> final output.
// ---------------------------------------------------------------------------
__global__ __launch_bounds__(256) void layer2_kernel(
    const int* __restrict__ head, const int* __restrict__ next,
    const int* __restrict__ edge_src,
    const float* __restrict__ fs2, const float* __restrict__ fn2,
    const float* __restrict__ h2, const float* __restrict__ b2,
    float* __restrict__ out) {
  int tid = blockIdx.x * 256 + threadIdx.x;   // n*4 + q
  if (tid >= N_NODES * 4) return;             // whole-wave exit (400000 % 64 == 0)
  int n = tid >> 2, q = tid & 3;
  float fs = fs2[n];

  float m = -1e30f, den = 0.f;
  float4 acc = make_float4(0.f, 0.f, 0.f, 0.f);
  int e = head[n];
  while (e >= 0) {
    int src = (e < NE) ? edge_src[e] : (e - NE);
    float l = fs + fn2[src];
    l = (l > 0.f) ? l : LEAKY * l;
    float mn = fmaxf(m, l);
    float r = __expf(m - mn);
    float w = __expf(l - mn);
    m = mn;
    float4 v = *(const float4*)(h2 + (size_t)src * NOUT + q * 4);
    den = den * r + w;
    acc.x = acc.x*r + w*v.x; acc.y = acc.y*r + w*v.y;
    acc.z = acc.z*r + w*v.z; acc.w = acc.w*r + w*v.w;
    e = next[e];
  }
  float inv = 1.f / (den + 1e-9f);
  const float4* bp = (const float4*)(b2 + q * 4);
  float4 bv = bp[0];
  float o0 = acc.x * inv + bv.x, o1 = acc.y * inv + bv.y;
  float o2 = acc.z * inv + bv.z, o3 = acc.w * inv + bv.w;

  // softmax over 16 channels across the 4-lane group
  float mx = fmaxf(fmaxf(o0, o1), fmaxf(o2, o3));
  mx = fmaxf(mx, __shfl_xor(mx, 1, 64));
  mx = fmaxf(mx, __shfl_xor(mx, 2, 64));
  float e0 = __expf(o0 - mx), e1 = __expf(o1 - mx);
  float e2 = __expf(o2 - mx), e3 = __expf(o3 - mx);
  float s = e0 + e1 + e2 + e3;
  s += __shfl_xor(s, 1, 64);
  s += __shfl_xor(s, 2, 64);
  float invs = 1.f / s;
  *(float4*)(out + (size_t)n * NOUT + q * 4) =
      make_float4(e0 * invs, e1 * invs, e2 * invs, e3 * invs);
}

// ---------------------------------------------------------------------------
extern "C" void kernel_launch(void* const* d_in, const int* in_sizes, int n_in,
                              void* d_out, int out_size, void* d_ws, size_t ws_size,
                              hipStream_t stream) {
  const float* x        = (const float*)d_in[0];
  const float* W1       = (const float*)d_in[1];
  const float* a_self1  = (const float*)d_in[2];
  const float* a_neigh1 = (const float*)d_in[3];
  const float* b1       = (const float*)d_in[4];
  const float* W2       = (const float*)d_in[5];
  const float* a_self2  = (const float*)d_in[6];
  const float* a_neigh2 = (const float*)d_in[7];
  const float* b2       = (const float*)d_in[8];
  const int* edge_src   = (const int*)d_in[9];
  const int* edge_dst   = (const int*)d_in[10];
  float* out = (float*)d_out;

  // workspace carve-out (all offsets 256B-aligned), total ~50 MB
  char* p = (char*)d_ws;
  auto alloc = [&](size_t bytes) -> void* {
    void* r = (void*)p;
    p += (bytes + 255) & ~(size_t)255;
    return r;
  };
  float* h1  = (float*)alloc((size_t)N_NODES * HC * 4);
  float* fs1 = (float*)alloc((size_t)N_NODES * HEADS * 4);
  float* fn1 = (float*)alloc((size_t)N_NODES * HEADS * 4);
  float* h2  = (float*)alloc((size_t)N_NODES * NOUT * 4);
  float* fs2 = (float*)alloc((size_t)N_NODES * 4);
  float* fn2 = (float*)alloc((size_t)N_NODES * 4);
  int* head  = (int*)alloc((size_t)N_NODES * 4);
  int* next  = (int*)alloc((size_t)E_TOT * 4);

  hipMemsetAsync(head, 0xFF, (size_t)N_NODES * 4, stream);   // head = -1

  gemm1_f1_kernel<<<(N_NODES + 63) / 64, 256, 0, stream>>>(
      x, W1, a_self1, a_neigh1, h1, fs1, fn1);
  ll_build_kernel<<<(E_TOT + 255) / 256, 256, 0, stream>>>(edge_dst, head, next);
  layer1_kernel<<<(N_NODES * HEADS) / 256, 256, 0, stream>>>(
      head, next, edge_src, fs1, fn1, h1, b1, W2, a_self2, a_neigh2, h2, fs2, fn2);
  layer2_kernel<<<(N_NODES * 4 + 255) / 256, 256, 0, stream>>>(
      head, next, edge_src, fs2, fn2, h2, b2, out);
}

// Round 3
// 756.997 us; speedup vs baseline: 1.6427x; 1.1775x over previous
//
#include <hip/hip_runtime.h>
#include <hip/hip_bf16.h>
#include <hip/hip_fp16.h>
#include <math.h>

#define N_NODES 100000
#define F_IN 512
#define HEADS 8
#define CH 8
#define HC 64           // HEADS*CH
#define NOUT 16
#define NE 3200000
#define E_TOT (NE + N_NODES)   // 3,300,000 (edges + self loops)
#define LEAKY 0.2f

// ---------------------------------------------------------------------------
// K1: h1[N,64] = x[N,512] @ W1[512,64]   (fp32 math, tiled BM=64 BN=64 BK=64)
//     xs stored TRANSPOSED [k][row] with XOR swizzle so the A-fragment read
//     is one ds_read_b128 (was 4x ds_read_b32). h1 written as fp16 (storage).
//     Fused epilogue: fs1/fn1[N,8] = per-head dot(h1[n,h,:], a_*[h,:]) (fp32).
// ---------------------------------------------------------------------------
__device__ __forceinline__ int xsw(int k) { return ((k >> 3) & 3) << 2; }

__global__ __launch_bounds__(256) void gemm1_f1_kernel(
    const float* __restrict__ x, const float* __restrict__ W,
    const float* __restrict__ a_self, const float* __restrict__ a_neigh,
    __half* __restrict__ h1h, float* __restrict__ fs1, float* __restrict__ fn1) {
  __shared__ __align__(16) float xs[64][68];   // [k][row^swz], stride 68 keeps 16B align
  __shared__ __align__(16) float ws[64][64];
  const int t  = threadIdx.x;
  const int bm = blockIdx.x * 64;
  const int ty = t >> 4, tx = t & 15;
  const int lr = t >> 4;      // 0..15
  const int lc = t & 15;      // 0..15 (float4 column)
  float acc[4][4] = {{0.f,0.f,0.f,0.f},{0.f,0.f,0.f,0.f},
                     {0.f,0.f,0.f,0.f},{0.f,0.f,0.f,0.f}};

  for (int k0 = 0; k0 < F_IN; k0 += 64) {
    #pragma unroll
    for (int i = 0; i < 4; i++) {              // x tile: 64 rows x 64 k (transposed store)
      int row = lr + i * 16;
      int gr  = bm + row;
      float4 v = make_float4(0.f, 0.f, 0.f, 0.f);
      if (gr < N_NODES)
        v = *(const float4*)(x + (size_t)gr * F_IN + k0 + lc * 4);
      int kk = lc * 4;
      xs[kk + 0][row ^ xsw(kk + 0)] = v.x;
      xs[kk + 1][row ^ xsw(kk + 1)] = v.y;
      xs[kk + 2][row ^ xsw(kk + 2)] = v.z;
      xs[kk + 3][row ^ xsw(kk + 3)] = v.w;
    }
    #pragma unroll
    for (int i = 0; i < 4; i++) {              // W tile: 64 k x 64 cols
      int kr = lr + i * 16;
      float4 v = *(const float4*)(W + (size_t)(k0 + kr) * HC + lc * 4);
      *(float4*)&ws[kr][lc * 4] = v;
    }
    __syncthreads();
    #pragma unroll 16
    for (int k = 0; k < 64; k++) {
      float4 a = *(const float4*)&xs[k][(ty * 4) ^ xsw(k)];   // rows ty*4..ty*4+3
      float4 b = *(const float4*)&ws[k][tx * 4];
      acc[0][0] += a.x * b.x; acc[0][1] += a.x * b.y; acc[0][2] += a.x * b.z; acc[0][3] += a.x * b.w;
      acc[1][0] += a.y * b.x; acc[1][1] += a.y * b.y; acc[1][2] += a.y * b.z; acc[1][3] += a.y * b.w;
      acc[2][0] += a.z * b.x; acc[2][1] += a.z * b.y; acc[2][2] += a.z * b.z; acc[2][3] += a.z * b.w;
      acc[3][0] += a.w * b.x; acc[3][1] += a.w * b.y; acc[3][2] += a.w * b.z; acc[3][3] += a.w * b.w;
    }
    __syncthreads();
  }

  // write h1 tile as fp16 (8B per thread-row)
  #pragma unroll
  for (int i = 0; i < 4; i++) {
    int gr = bm + ty * 4 + i;
    if (gr < N_NODES) {
      union { __half2 h2[2]; uint2 u; } pk;
      pk.h2[0] = __floats2half2_rn(acc[i][0], acc[i][1]);
      pk.h2[1] = __floats2half2_rn(acc[i][2], acc[i][3]);
      *(uint2*)(h1h + (size_t)gr * HC + tx * 4) = pk.u;
    }
  }

  // fused f1 from fp32 accumulators: this thread's 4 cols = half of head h = tx>>1
  const int h    = tx >> 1;
  const int part = tx & 1;
  float4 asv = *(const float4*)(a_self  + h * 8 + part * 4);
  float4 anv = *(const float4*)(a_neigh + h * 8 + part * 4);
  #pragma unroll
  for (int i = 0; i < 4; i++) {
    float ps = acc[i][0]*asv.x + acc[i][1]*asv.y + acc[i][2]*asv.z + acc[i][3]*asv.w;
    float pn = acc[i][0]*anv.x + acc[i][1]*anv.y + acc[i][2]*anv.z + acc[i][3]*anv.w;
    ps += __shfl_xor(ps, 1, 64);
    pn += __shfl_xor(pn, 1, 64);
    int gr = bm + ty * 4 + i;
    if (part == 0 && gr < N_NODES) {
      fs1[gr * 8 + h] = ps;
      fn1[gr * 8 + h] = pn;
    }
  }
}

// ---------------------------------------------------------------------------
// K2: linked-list build — link[e] = {next, src}; one 8B record per edge so the
//     walk does a single broadcast load per step. head pre-memset to -1.
// ---------------------------------------------------------------------------
__global__ __launch_bounds__(256) void ll_build_kernel(
    const int* __restrict__ edge_src, const int* __restrict__ edge_dst,
    int* __restrict__ head, int2* __restrict__ link) {
  int e = blockIdx.x * 256 + threadIdx.x;
  if (e >= E_TOT) return;
  int s, d;
  if (e < NE) { s = edge_src[e]; d = edge_dst[e]; }
  else        { s = e - NE;      d = e - NE; }
  int prev = atomicExch(&head[d], e);
  link[e] = make_int2(prev, s);
}

// ---------------------------------------------------------------------------
// K3: layer-1 aggregation. 8 lanes per node (one per head).
//     Single online-softmax walk over the linked list, then fused
//     bias+ELU -> h2 = out1 @ W2 -> f_self2/f_neigh2.
// grid = N*HEADS = 800000 threads exactly (3125*256)
// ---------------------------------------------------------------------------
__global__ __launch_bounds__(256) void layer1_kernel(
    const int* __restrict__ head, const int2* __restrict__ link,
    const float* __restrict__ fs1, const float* __restrict__ fn1,
    const __half* __restrict__ h1h, const float* __restrict__ b1,
    const float* __restrict__ W2, const float* __restrict__ a_self2,
    const float* __restrict__ a_neigh2, float* __restrict__ h2,
    float* __restrict__ fs2, float* __restrict__ fn2) {
  __shared__ float w2s[HC][NOUT];
  for (int i = threadIdx.x; i < HC * NOUT; i += 256)
    w2s[i / NOUT][i % NOUT] = W2[i];
  __syncthreads();

  int tid = blockIdx.x * 256 + threadIdx.x;   // n*8 + h
  int n = tid >> 3, h = tid & 7;
  float fs = fs1[tid];

  // online-softmax walk (branchless rescale; exact: final m == true max)
  float m = -1e30f, den = 0.f;
  float acc[CH] = {0.f,0.f,0.f,0.f,0.f,0.f,0.f,0.f};
  int e = head[n];
  while (e >= 0) {
    int2 ln = link[e];                 // 8B broadcast across the 8 lanes
    int src = ln.y;
    float l = fs + fn1[src * HEADS + h];
    l = (l > 0.f) ? l : LEAKY * l;
    float mn = fmaxf(m, l);
    float r = __expf(m - mn);          // 1 when no new max; 0 on first edge
    float w = __expf(l - mn);
    m = mn;
    float4 raw = *(const float4*)(h1h + (size_t)src * HC + h * CH);  // 8 halves
    const __half2* hh = (const __half2*)&raw;
    float2 f0 = __half22float2(hh[0]), f1v = __half22float2(hh[1]);
    float2 f2 = __half22float2(hh[2]), f3v = __half22float2(hh[3]);
    den = den * r + w;
    acc[0] = acc[0]*r + w*f0.x;  acc[1] = acc[1]*r + w*f0.y;
    acc[2] = acc[2]*r + w*f1v.x; acc[3] = acc[3]*r + w*f1v.y;
    acc[4] = acc[4]*r + w*f2.x;  acc[5] = acc[5]*r + w*f2.y;
    acc[6] = acc[6]*r + w*f3v.x; acc[7] = acc[7]*r + w*f3v.y;
    e = ln.x;
  }
  float inv = 1.f / (den + 1e-9f);

  // bias + ELU (this lane's 8 channels of the 64-wide concat output)
  const float4* bp = (const float4*)(b1 + h * 8);
  float4 b0 = bp[0], b1v = bp[1];
  float o[CH];
  o[0] = acc[0]*inv + b0.x; o[1] = acc[1]*inv + b0.y;
  o[2] = acc[2]*inv + b0.z; o[3] = acc[3]*inv + b0.w;
  o[4] = acc[4]*inv + b1v.x; o[5] = acc[5]*inv + b1v.y;
  o[6] = acc[6]*inv + b1v.z; o[7] = acc[7]*inv + b1v.w;
  #pragma unroll
  for (int c = 0; c < CH; c++) o[c] = (o[c] > 0.f) ? o[c] : expm1f(o[c]);

  // fused layer-2 projection: h2[n, :] = out1[n, :] @ W2[64,16]
  float pj[NOUT];
  #pragma unroll
  for (int c2 = 0; c2 < NOUT; c2++) {
    float s = 0.f;
    #pragma unroll
    for (int c = 0; c < CH; c++) s += o[c] * w2s[h * CH + c][c2];
    pj[c2] = s;
  }
  // butterfly-sum over the 8 head-lanes of this node
  #pragma unroll
  for (int mm = 1; mm < 8; mm <<= 1) {
    #pragma unroll
    for (int c2 = 0; c2 < NOUT; c2++)
      pj[c2] += __shfl_xor(pj[c2], mm, 64);
  }
  // coalesced h2 write: lane h writes elements [h*2, h*2+1]
  *(float2*)(h2 + (size_t)n * NOUT + h * 2) = make_float2(pj[h * 2], pj[h * 2 + 1]);
  if (h == 0) {
    float s1 = 0.f, s2 = 0.f;
    #pragma unroll
    for (int c2 = 0; c2 < NOUT; c2++) {
      s1 += pj[c2] * a_self2[c2];
      s2 += pj[c2] * a_neigh2[c2];
    }
    fs2[n] = s1;
    fn2[n] = s2;
  }
}

// ---------------------------------------------------------------------------
// K4: layer-2 aggregation (1 head, 16 ch). 4 lanes per node, 4 ch each.
//     Single online-softmax walk. Fused: bias + row-softmax -> final output.
// ---------------------------------------------------------------------------
__global__ __launch_bounds__(256) void layer2_kernel(
    const int* __restrict__ head, const int2* __restrict__ link,
    const float* __restrict__ fs2, const float* __restrict__ fn2,
    const float* __restrict__ h2, const float* __restrict__ b2,
    float* __restrict__ out) {
  int tid = blockIdx.x * 256 + threadIdx.x;   // n*4 + q
  if (tid >= N_NODES * 4) return;             // whole-wave exit (400000 % 64 == 0)
  int n = tid >> 2, q = tid & 3;
  float fs = fs2[n];

  float m = -1e30f, den = 0.f;
  float4 acc = make_float4(0.f, 0.f, 0.f, 0.f);
  int e = head[n];
  while (e >= 0) {
    int2 ln = link[e];
    int src = ln.y;
    float l = fs + fn2[src];
    l = (l > 0.f) ? l : LEAKY * l;
    float mn = fmaxf(m, l);
    float r = __expf(m - mn);
    float w = __expf(l - mn);
    m = mn;
    float4 v = *(const float4*)(h2 + (size_t)src * NOUT + q * 4);
    den = den * r + w;
    acc.x = acc.x*r + w*v.x; acc.y = acc.y*r + w*v.y;
    acc.z = acc.z*r + w*v.z; acc.w = acc.w*r + w*v.w;
    e = ln.x;
  }
  float inv = 1.f / (den + 1e-9f);
  const float4* bp = (const float4*)(b2 + q * 4);
  float4 bv = bp[0];
  float o0 = acc.x * inv + bv.x, o1 = acc.y * inv + bv.y;
  float o2 = acc.z * inv + bv.z, o3 = acc.w * inv + bv.w;

  // softmax over 16 channels across the 4-lane group
  float mx = fmaxf(fmaxf(o0, o1), fmaxf(o2, o3));
  mx = fmaxf(mx, __shfl_xor(mx, 1, 64));
  mx = fmaxf(mx, __shfl_xor(mx, 2, 64));
  float e0 = __expf(o0 - mx), e1 = __expf(o1 - mx);
  float e2 = __expf(o2 - mx), e3 = __expf(o3 - mx);
  float s = e0 + e1 + e2 + e3;
  s += __shfl_xor(s, 1, 64);
  s += __shfl_xor(s, 2, 64);
  float invs = 1.f / s;
  *(float4*)(out + (size_t)n * NOUT + q * 4) =
      make_float4(e0 * invs, e1 * invs, e2 * invs, e3 * invs);
}

// ---------------------------------------------------------------------------
extern "C" void kernel_launch(void* const* d_in, const int* in_sizes, int n_in,
                              void* d_out, int out_size, void* d_ws, size_t ws_size,
                              hipStream_t stream) {
  const float* x        = (const float*)d_in[0];
  const float* W1       = (const float*)d_in[1];
  const float* a_self1  = (const float*)d_in[2];
  const float* a_neigh1 = (const float*)d_in[3];
  const float* b1       = (const float*)d_in[4];
  const float* W2       = (const float*)d_in[5];
  const float* a_self2  = (const float*)d_in[6];
  const float* a_neigh2 = (const float*)d_in[7];
  const float* b2       = (const float*)d_in[8];
  const int* edge_src   = (const int*)d_in[9];
  const int* edge_dst   = (const int*)d_in[10];
  float* out = (float*)d_out;

  // workspace carve-out (all offsets 256B-aligned), total ~48 MB
  char* p = (char*)d_ws;
  auto alloc = [&](size_t bytes) -> void* {
    void* r = (void*)p;
    p += (bytes + 255) & ~(size_t)255;
    return r;
  };
  __half* h1h = (__half*)alloc((size_t)N_NODES * HC * 2);
  float* fs1 = (float*)alloc((size_t)N_NODES * HEADS * 4);
  float* fn1 = (float*)alloc((size_t)N_NODES * HEADS * 4);
  float* h2  = (float*)alloc((size_t)N_NODES * NOUT * 4);
  float* fs2 = (float*)alloc((size_t)N_NODES * 4);
  float* fn2 = (float*)alloc((size_t)N_NODES * 4);
  int*  head = (int*)alloc((size_t)N_NODES * 4);
  int2* link = (int2*)alloc((size_t)E_TOT * 8);

  hipMemsetAsync(head, 0xFF, (size_t)N_NODES * 4, stream);   // head = -1

  gemm1_f1_kernel<<<(N_NODES + 63) / 64, 256, 0, stream>>>(
      x, W1, a_self1, a_neigh1, h1h, fs1, fn1);
  ll_build_kernel<<<(E_TOT + 255) / 256, 256, 0, stream>>>(
      edge_src, edge_dst, head, link);
  layer1_kernel<<<(N_NODES * HEADS) / 256, 256, 0, stream>>>(
      head, link, fs1, fn1, h1h, b1, W2, a_self2, a_neigh2, h2, fs2, fn2);
  layer2_kernel<<<(N_NODES * 4 + 255) / 256, 256, 0, stream>>>(
      head, link, fs2, fn2, h2, b2, out);
}

// Round 5
// 679.913 us; speedup vs baseline: 1.8289x; 1.1134x over previous
//
#include <hip/hip_runtime.h>
#include <hip/hip_bf16.h>
#include <hip/hip_fp16.h>
#include <math.h>

#define N_NODES 100000
#define F_IN 512
#define HEADS 8
#define CH 8
#define HC 64           // HEADS*CH
#define NOUT 16
#define NE 3200000
#define E_TOT (NE + N_NODES)   // 3,300,000 (edges + self loops)
#define LEAKY 0.2f

// ---------------------------------------------------------------------------
// Edge-phase helper: linked-list build — link[e] = {next, src}
// next[] write coalesced by e; atomics hit a 400 KB head[] array.
// ---------------------------------------------------------------------------
__device__ __forceinline__ void build_edges(
    int gtid, int nthreads, const int* __restrict__ edge_src,
    const int* __restrict__ edge_dst, int* __restrict__ head,
    int2* __restrict__ link) {
  for (int e = gtid; e < E_TOT; e += nthreads) {
    int s, d;
    if (e < NE) { s = edge_src[e]; d = edge_dst[e]; }
    else        { s = e - NE;      d = e - NE; }
    int prev = atomicExch(&head[d], e);
    link[e] = make_int2(prev, s);
  }
}

// ---------------------------------------------------------------------------
// K1 (fused): h1[N,64] = x[N,512] @ W1[512,64] (fp32 math, BM=64 BK=64)
//   + staggered linked-list build (odd blocks before GEMM, even blocks after)
//     — ll is memory/atomic-bound, GEMM is LDS/VALU-bound: disjoint pipes.
//   xs stored TRANSPOSED [k][row^swz] so the A-read is one ds_read_b128.
//   h1 written fp16 (storage only). Fused f1 epilogue from fp32 accumulators.
// ---------------------------------------------------------------------------
__device__ __forceinline__ int xsw(int k) { return ((k >> 3) & 3) << 2; }

__global__ __launch_bounds__(256) void gemm1_f1_ll_kernel(
    const float* __restrict__ x, const float* __restrict__ W,
    const float* __restrict__ a_self, const float* __restrict__ a_neigh,
    const int* __restrict__ edge_src, const int* __restrict__ edge_dst,
    int* __restrict__ head, int2* __restrict__ link,
    __half* __restrict__ h1h, float* __restrict__ fs1, float* __restrict__ fn1) {
  __shared__ __align__(16) float xs[64][68];   // [k][row^swz], stride 68 keeps 16B align
  __shared__ __align__(16) float ws[64][64];
  const int t  = threadIdx.x;
  const int bm = blockIdx.x * 64;
  const int gtid = blockIdx.x * 256 + t;
  const int nthreads = gridDim.x * 256;

  if (blockIdx.x & 1)
    build_edges(gtid, nthreads, edge_src, edge_dst, head, link);

  const int ty = t >> 4, tx = t & 15;
  const int lr = t >> 4;      // 0..15
  const int lc = t & 15;      // 0..15 (float4 column)
  float acc[4][4] = {{0.f,0.f,0.f,0.f},{0.f,0.f,0.f,0.f},
                     {0.f,0.f,0.f,0.f},{0.f,0.f,0.f,0.f}};

  for (int k0 = 0; k0 < F_IN; k0 += 64) {
    #pragma unroll
    for (int i = 0; i < 4; i++) {              // x tile: 64 rows x 64 k (transposed store)
      int row = lr + i * 16;
      int gr  = bm + row;
      float4 v = make_float4(0.f, 0.f, 0.f, 0.f);
      if (gr < N_NODES)
        v = *(const float4*)(x + (size_t)gr * F_IN + k0 + lc * 4);
      int kk = lc * 4;
      xs[kk + 0][row ^ xsw(kk + 0)] = v.x;
      xs[kk + 1][row ^ xsw(kk + 1)] = v.y;
      xs[kk + 2][row ^ xsw(kk + 2)] = v.z;
      xs[kk + 3][row ^ xsw(kk + 3)] = v.w;
    }
    #pragma unroll
    for (int i = 0; i < 4; i++) {              // W tile: 64 k x 64 cols
      int kr = lr + i * 16;
      float4 v = *(const float4*)(W + (size_t)(k0 + kr) * HC + lc * 4);
      *(float4*)&ws[kr][lc * 4] = v;
    }
    __syncthreads();
    #pragma unroll 16
    for (int k = 0; k < 64; k++) {
      float4 a = *(const float4*)&xs[k][(ty * 4) ^ xsw(k)];   // rows ty*4..ty*4+3
      float4 b = *(const float4*)&ws[k][tx * 4];
      acc[0][0] += a.x * b.x; acc[0][1] += a.x * b.y; acc[0][2] += a.x * b.z; acc[0][3] += a.x * b.w;
      acc[1][0] += a.y * b.x; acc[1][1] += a.y * b.y; acc[1][2] += a.y * b.z; acc[1][3] += a.y * b.w;
      acc[2][0] += a.z * b.x; acc[2][1] += a.z * b.y; acc[2][2] += a.z * b.z; acc[2][3] += a.z * b.w;
      acc[3][0] += a.w * b.x; acc[3][1] += a.w * b.y; acc[3][2] += a.w * b.z; acc[3][3] += a.w * b.w;
    }
    __syncthreads();
  }

  // write h1 tile as fp16 (8B per thread-row)
  #pragma unroll
  for (int i = 0; i < 4; i++) {
    int gr = bm + ty * 4 + i;
    if (gr < N_NODES) {
      union { __half2 h2[2]; uint2 u; } pk;
      pk.h2[0] = __floats2half2_rn(acc[i][0], acc[i][1]);
      pk.h2[1] = __floats2half2_rn(acc[i][2], acc[i][3]);
      *(uint2*)(h1h + (size_t)gr * HC + tx * 4) = pk.u;
    }
  }

  // fused f1 from fp32 accumulators: this thread's 4 cols = half of head h = tx>>1
  const int h    = tx >> 1;
  const int part = tx & 1;
  float4 asv = *(const float4*)(a_self  + h * 8 + part * 4);
  float4 anv = *(const float4*)(a_neigh + h * 8 + part * 4);
  #pragma unroll
  for (int i = 0; i < 4; i++) {
    float ps = acc[i][0]*asv.x + acc[i][1]*asv.y + acc[i][2]*asv.z + acc[i][3]*asv.w;
    float pn = acc[i][0]*anv.x + acc[i][1]*anv.y + acc[i][2]*anv.z + acc[i][3]*anv.w;
    ps += __shfl_xor(ps, 1, 64);
    pn += __shfl_xor(pn, 1, 64);
    int gr = bm + ty * 4 + i;
    if (part == 0 && gr < N_NODES) {
      fs1[gr * 8 + h] = ps;
      fn1[gr * 8 + h] = pn;
    }
  }

  if (!(blockIdx.x & 1))
    build_edges(gtid, nthreads, edge_src, edge_dst, head, link);
}

// ---------------------------------------------------------------------------
// K3: layer-1 aggregation. 8 lanes per node (one per head).
//     Single online-softmax walk over the linked list, then fused
//     bias+ELU -> h2 = out1 @ W2 -> f_self2/f_neigh2.
// grid = N*HEADS = 800000 threads exactly (3125*256)
// ---------------------------------------------------------------------------
__global__ __launch_bounds__(256) void layer1_kernel(
    const int* __restrict__ head, const int2* __restrict__ link,
    const float* __restrict__ fs1, const float* __restrict__ fn1,
    const __half* __restrict__ h1h, const float* __restrict__ b1,
    const float* __restrict__ W2, const float* __restrict__ a_self2,
    const float* __restrict__ a_neigh2, float* __restrict__ h2,
    float* __restrict__ fs2, float* __restrict__ fn2) {
  __shared__ float w2s[HC][NOUT];
  for (int i = threadIdx.x; i < HC * NOUT; i += 256)
    w2s[i / NOUT][i % NOUT] = W2[i];
  __syncthreads();

  int tid = blockIdx.x * 256 + threadIdx.x;   // n*8 + h
  int n = tid >> 3, h = tid & 7;
  float fs = fs1[tid];

  // online-softmax walk (branchless rescale; exact: final m == true max)
  float m = -1e30f, den = 0.f;
  float acc[CH] = {0.f,0.f,0.f,0.f,0.f,0.f,0.f,0.f};
  int e = head[n];
  while (e >= 0) {
    int2 ln = link[e];                 // 8B broadcast across the 8 lanes
    int src = ln.y;
    float l = fs + fn1[src * HEADS + h];
    l = (l > 0.f) ? l : LEAKY * l;
    float mn = fmaxf(m, l);
    float r = __expf(m - mn);          // 1 when no new max; 0 on first edge
    float w = __expf(l - mn);
    m = mn;
    float4 raw = *(const float4*)(h1h + (size_t)src * HC + h * CH);  // 8 halves
    const __half2* hh = (const __half2*)&raw;
    float2 f0 = __half22float2(hh[0]), f1v = __half22float2(hh[1]);
    float2 f2 = __half22float2(hh[2]), f3v = __half22float2(hh[3]);
    den = den * r + w;
    acc[0] = acc[0]*r + w*f0.x;  acc[1] = acc[1]*r + w*f0.y;
    acc[2] = acc[2]*r + w*f1v.x; acc[3] = acc[3]*r + w*f1v.y;
    acc[4] = acc[4]*r + w*f2.x;  acc[5] = acc[5]*r + w*f2.y;
    acc[6] = acc[6]*r + w*f3v.x; acc[7] = acc[7]*r + w*f3v.y;
    e = ln.x;
  }
  float inv = 1.f / (den + 1e-9f);

  // bias + ELU (this lane's 8 channels of the 64-wide concat output)
  const float4* bp = (const float4*)(b1 + h * 8);
  float4 b0 = bp[0], b1v = bp[1];
  float o[CH];
  o[0] = acc[0]*inv + b0.x; o[1] = acc[1]*inv + b0.y;
  o[2] = acc[2]*inv + b0.z; o[3] = acc[3]*inv + b0.w;
  o[4] = acc[4]*inv + b1v.x; o[5] = acc[5]*inv + b1v.y;
  o[6] = acc[6]*inv + b1v.z; o[7] = acc[7]*inv + b1v.w;
  #pragma unroll
  for (int c = 0; c < CH; c++) o[c] = (o[c] > 0.f) ? o[c] : expm1f(o[c]);

  // fused layer-2 projection: h2[n, :] = out1[n, :] @ W2[64,16]
  float pj[NOUT];
  #pragma unroll
  for (int c2 = 0; c2 < NOUT; c2++) {
    float s = 0.f;
    #pragma unroll
    for (int c = 0; c < CH; c++) s += o[c] * w2s[h * CH + c][c2];
    pj[c2] = s;
  }
  // butterfly-sum over the 8 head-lanes of this node
  #pragma unroll
  for (int mm = 1; mm < 8; mm <<= 1) {
    #pragma unroll
    for (int c2 = 0; c2 < NOUT; c2++)
      pj[c2] += __shfl_xor(pj[c2], mm, 64);
  }
  // coalesced h2 write: lane h writes elements [h*2, h*2+1]
  *(float2*)(h2 + (size_t)n * NOUT + h * 2) = make_float2(pj[h * 2], pj[h * 2 + 1]);
  if (h == 0) {
    float s1 = 0.f, s2 = 0.f;
    #pragma unroll
    for (int c2 = 0; c2 < NOUT; c2++) {
      s1 += pj[c2] * a_self2[c2];
      s2 += pj[c2] * a_neigh2[c2];
    }
    fs2[n] = s1;
    fn2[n] = s2;
  }
}

// ---------------------------------------------------------------------------
// K4: layer-2 aggregation (1 head, 16 ch). 4 lanes per node, 4 ch each.
//     Single online-softmax walk. Fused: bias + row-softmax -> final output.
// ---------------------------------------------------------------------------
__global__ __launch_bounds__(256) void layer2_kernel(
    const int* __restrict__ head, const int2* __restrict__ link,
    const float* __restrict__ fs2, const float* __restrict__ fn2,
    const float* __restrict__ h2, const float* __restrict__ b2,
    float* __restrict__ out) {
  int tid = blockIdx.x * 256 + threadIdx.x;   // n*4 + q
  if (tid >= N_NODES * 4) return;             // whole-wave exit (400000 % 64 == 0)
  int n = tid >> 2, q = tid & 3;
  float fs = fs2[n];

  float m = -1e30f, den = 0.f;
  float4 acc = make_float4(0.f, 0.f, 0.f, 0.f);
  int e = head[n];
  while (e >= 0) {
    int2 ln = link[e];
    int src = ln.y;
    float l = fs + fn2[src];
    l = (l > 0.f) ? l : LEAKY * l;
    float mn = fmaxf(m, l);
    float r = __expf(m - mn);
    float w = __expf(l - mn);
    m = mn;
    float4 v = *(const float4*)(h2 + (size_t)src * NOUT + q * 4);
    den = den * r + w;
    acc.x = acc.x*r + w*v.x; acc.y = acc.y*r + w*v.y;
    acc.z = acc.z*r + w*v.z; acc.w = acc.w*r + w*v.w;
    e = ln.x;
  }
  float inv = 1.f / (den + 1e-9f);
  const float4* bp = (const float4*)(b2 + q * 4);
  float4 bv = bp[0];
  float o0 = acc.x * inv + bv.x, o1 = acc.y * inv + bv.y;
  float o2 = acc.z * inv + bv.z, o3 = acc.w * inv + bv.w;

  // softmax over 16 channels across the 4-lane group
  float mx = fmaxf(fmaxf(o0, o1), fmaxf(o2, o3));
  mx = fmaxf(mx, __shfl_xor(mx, 1, 64));
  mx = fmaxf(mx, __shfl_xor(mx, 2, 64));
  float e0 = __expf(o0 - mx), e1 = __expf(o1 - mx);
  float e2 = __expf(o2 - mx), e3 = __expf(o3 - mx);
  float s = e0 + e1 + e2 + e3;
  s += __shfl_xor(s, 1, 64);
  s += __shfl_xor(s, 2, 64);
  float invs = 1.f / s;
  *(float4*)(out + (size_t)n * NOUT + q * 4) =
      make_float4(e0 * invs, e1 * invs, e2 * invs, e3 * invs);
}

// ---------------------------------------------------------------------------
extern "C" void kernel_launch(void* const* d_in, const int* in_sizes, int n_in,
                              void* d_out, int out_size, void* d_ws, size_t ws_size,
                              hipStream_t stream) {
  const float* x        = (const float*)d_in[0];
  const float* W1       = (const float*)d_in[1];
  const float* a_self1  = (const float*)d_in[2];
  const float* a_neigh1 = (const float*)d_in[3];
  const float* b1       = (const float*)d_in[4];
  const float* W2       = (const float*)d_in[5];
  const float* a_self2  = (const float*)d_in[6];
  const float* a_neigh2 = (const float*)d_in[7];
  const float* b2       = (const float*)d_in[8];
  const int* edge_src   = (const int*)d_in[9];
  const int* edge_dst   = (const int*)d_in[10];
  float* out = (float*)d_out;

  // workspace carve-out (all offsets 256B-aligned), total ~48 MB
  char* p = (char*)d_ws;
  auto alloc = [&](size_t bytes) -> void* {
    void* r = (void*)p;
    p += (bytes + 255) & ~(size_t)255;
    return r;
  };
  __half* h1h = (__half*)alloc((size_t)N_NODES * HC * 2);
  float* fs1 = (float*)alloc((size_t)N_NODES * HEADS * 4);
  float* fn1 = (float*)alloc((size_t)N_NODES * HEADS * 4);
  float* h2  = (float*)alloc((size_t)N_NODES * NOUT * 4);
  float* fs2 = (float*)alloc((size_t)N_NODES * 4);
  float* fn2 = (float*)alloc((size_t)N_NODES * 4);
  int*  head = (int*)alloc((size_t)N_NODES * 4);
  int2* link = (int2*)alloc((size_t)E_TOT * 8);

  hipMemsetAsync(head, 0xFF, (size_t)N_NODES * 4, stream);   // head = -1

  gemm1_f1_ll_kernel<<<(N_NODES + 63) / 64, 256, 0, stream>>>(
      x, W1, a_self1, a_neigh1, edge_src, edge_dst, head, link, h1h, fs1, fn1);
  layer1_kernel<<<(N_NODES * HEADS) / 256, 256, 0, stream>>>(
      head, link, fs1, fn1, h1h, b1, W2, a_self2, a_neigh2, h2, fs2, fn2);
  layer2_kernel<<<(N_NODES * 4 + 255) / 256, 256, 0, stream>>>(
      head, link, fs2, fn2, h2, b2, out);
}